// Round 8
// baseline (239.082 us; speedup 1.0000x reference)
//
#include <hip/hip_runtime.h>

#define B_ 512
#define T_ 512
#define C_ 128
#define L_ 80
#define BLANK_ 127
#define EPS_ 1e-7f
#define LN2_ 0.6931471805599453f

// raw v_log_f32 (base-2); __log2f collides with glibc math.h reserved names.
#define LOG2F(x) __builtin_amdgcn_logf(x)

// DPP cross-lane ops (VALU pipe).
template <int CTRL> __device__ __forceinline__ int dpp_i(int x) {
  return __builtin_amdgcn_update_dpp(0, x, CTRL, 0xF, 0xF, true);
}
template <int CTRL> __device__ __forceinline__ float dpp_f(float x) {
  return __int_as_float(
      __builtin_amdgcn_update_dpp(0, __float_as_int(x), CTRL, 0xF, 0xF, true));
}
#define DPP_WSHR1 0x138   // wave shift right 1 (lane0 -> 0 via bound_ctrl)
#define DPP_XOR1  0xB1
#define DPP_XOR2  0x4E
#define DPP_HMIRR 0x141
#define DPP_MIRR  0x140

// TWO independent CTC chains per wave (batches 2g, 2g+1), interleaved at the
// step level: whatever per-step latency stalls chain A is hidden by chain B's
// independent instructions. Linear-prob DP with per-lane exponent E (rescale
// per 8-step block); 3-deep global prefetch per chain; double-buffered LDS
// gathers; blank column via v_readlane (wave-uniform). Denominator factors
// out of the DP and is fused into staging.
__global__ __launch_bounds__(64, 1) void ctc_fused(
    const int* __restrict__ labels,     // [B,L]
    const float* __restrict__ y_pred,   // [B,T,C]
    float* __restrict__ out)            // [B,1]
{
  const int g = blockIdx.x, lane = threadIdx.x;
  const int ba = 2 * g, bb = 2 * g + 1;
  const float4* rpA = (const float4*)(y_pred + (size_t)ba * T_ * C_);
  const float4* rpB = (const float4*)(y_pred + (size_t)bb * T_ * C_);
  __shared__ float ring[2 * 2 * 8 * C_];   // [chain][bank][8][128]

  const int rgrp = lane >> 3, j16 = lane & 7;
  const bool evn = ((lane & 1) == 0);

  // ---- static per-lane symbols + skip masks, per chain ----
  auto labAt = [&](int bidx, int k) -> int {
    return (k >= 0 && k < L_) ? labels[bidx * L_ + k] : BLANK_;
  };
  int xpa, xsa, xpb, xsb;
  float m0a, m1a, m2a, m0b, m1b, m2b;
  {
    if (evn) {
      const int k1 = (3 * lane) >> 1;
      const int e = labAt(ba, k1);
      xpa = e; xsa = BLANK_;
      m0a = 0.f; m2a = 0.f;
      m1a = ((k1 < L_) && (k1 == 0 || e != labAt(ba, k1 - 1))) ? 1.f : 0.f;
      const int e2 = labAt(bb, k1);
      xpb = e2; xsb = BLANK_;
      m0b = 0.f; m2b = 0.f;
      m1b = ((k1 < L_) && (k1 == 0 || e2 != labAt(bb, k1 - 1))) ? 1.f : 0.f;
    } else {
      const int k0 = (3 * lane - 1) >> 1, k2 = k0 + 1;
      const int ea = labAt(ba, k0), eb = labAt(ba, k2);
      xpa = ea; xsa = eb;
      m0a = ((k0 < L_) && (k0 == 0 || ea != labAt(ba, k0 - 1))) ? 1.f : 0.f;
      m1a = 0.f;
      m2a = ((k2 < L_) && (eb != ea)) ? 1.f : 0.f;
      const int ea2 = labAt(bb, k0), eb2 = labAt(bb, k2);
      xpb = ea2; xsb = eb2;
      m0b = ((k0 < L_) && (k0 == 0 || ea2 != labAt(bb, k0 - 1))) ? 1.f : 0.f;
      m1b = 0.f;
      m2b = ((k2 < L_) && (eb2 != ea2)) ? 1.f : 0.f;
    }
  }

  float SaccA = 0.f, SaccB = 0.f;
  float A0a, A1a, A2a, A0b, A1b, A2b;
  int Ea = 0, Eb = 0;

  auto gload = [&](const float4* rp, float4 (&S)[4], int blk) {
    int row = blk * 8 + rgrp; if (row > T_ - 1) row = T_ - 1;
    const float4* src = rp + row * 32 + 4 * j16;
    #pragma unroll
    for (int k = 0; k < 4; ++k) S[k] = src[k];
  };
  auto prep = [&](float4 (&Sw)[4], float* ringc, int bankDst,
                  float (&bl)[8], float& SaccC) {
    #pragma unroll
    for (int k = 0; k < 4; ++k) {
      Sw[k].x += EPS_; Sw[k].y += EPS_; Sw[k].z += EPS_; Sw[k].w += EPS_;
    }
    float4* wd = (float4*)(ringc + bankDst * 1024 + rgrp * C_ + 16 * j16);
    #pragma unroll
    for (int k = 0; k < 4; ++k) wd[k] = Sw[k];
    float s = 0.f;
    #pragma unroll
    for (int k = 0; k < 4; ++k) s += (Sw[k].x + Sw[k].y) + (Sw[k].z + Sw[k].w);
    s += dpp_f<DPP_XOR1>(s);
    s += dpp_f<DPP_XOR2>(s);
    s += dpp_f<DPP_HMIRR>(s);
    SaccC += LOG2F(s);                  // 8x redundant per row; /8 at the end
    #pragma unroll
    for (int j = 0; j < 8; ++j)
      bl[j] = __int_as_float(
          __builtin_amdgcn_readlane(__float_as_int(Sw[3].w), 8 * j + 7));
  };
  auto gath = [&](const float* ringc, int bank, int xpC, int xsC,
                  float (&r1)[8], float (&r2)[8]) {
    const float* rb = ringc + bank * 1024;
    #pragma unroll
    for (int j = 0; j < 8; ++j) {
      r1[j] = rb[j * C_ + xpC];
      r2[j] = rb[j * C_ + xsC];
    }
  };

  float r1A[2][8], r2A[2][8], blA[2][8];
  float r1B[2][8], r2B[2][8], blB[2][8];
  float* ringA = ring;
  float* ringB = ring + 2048;

  // step-interleaved double-chain DP over one 8-step block
  auto dp8_2 = [&](float (&q1A)[8], float (&q2A)[8], float (&qbA)[8],
                   float (&q1B)[8], float (&q2B)[8], float (&qbB)[8]) {
    const int ELa = dpp_i<DPP_WSHR1>(Ea); const int da = Ea - ELa;
    const int ELb = dpp_i<DPP_WSHR1>(Eb); const int db = Eb - ELb;
    #pragma unroll
    for (int j = 0; j < 8; ++j) {
      float p1a = dpp_f<DPP_WSHR1>(A1a), p2a = dpp_f<DPP_WSHR1>(A2a);
      float p1b = dpp_f<DPP_WSHR1>(A1b), p2b = dpp_f<DPP_WSHR1>(A2b);
      p1a = ldexpf(p1a, da); p2a = ldexpf(p2a, da);
      p1b = ldexpf(p1b, db); p2b = ldexpf(p2b, db);
      const float q0a = evn ? q2A[j] : q1A[j];
      const float q1av = evn ? q1A[j] : qbA[j];
      const float q0b = evn ? q2B[j] : q1B[j];
      const float q1bv = evn ? q1B[j] : qbB[j];
      const float t0a = q0a   * fmaf(m0a, p1a, A0a + p2a);
      const float t0b = q0b   * fmaf(m0b, p1b, A0b + p2b);
      const float t1a = q1av  * fmaf(m1a, p2a, A1a + A0a);
      const float t1b = q1bv  * fmaf(m1b, p2b, A1b + A0b);
      const float t2a = q2A[j]* fmaf(m2a, A0a, A2a + A1a);
      const float t2b = q2B[j]* fmaf(m2b, A0b, A2b + A1b);
      A0a = t0a; A1a = t1a; A2a = t2a;
      A0b = t0b; A1b = t1b; A2b = t2b;
    }
    // rescale both chains
    {
      const float mxa = fmaxf(fmaxf(A0a, A1a), A2a);
      const float mxb = fmaxf(fmaxf(A0b, A1b), A2b);
      int eea = (int)((__float_as_uint(mxa) >> 23) & 255u) - 127;
      int eeb = (int)((__float_as_uint(mxb) >> 23) & 255u) - 127;
      const bool za = (mxa == 0.f), zb = (mxb == 0.f);
      eea = za ? 0 : eea; eeb = zb ? 0 : eeb;
      A0a = ldexpf(A0a, -eea); A1a = ldexpf(A1a, -eea); A2a = ldexpf(A2a, -eea);
      A0b = ldexpf(A0b, -eeb); A1b = ldexpf(A1b, -eeb); A2b = ldexpf(A2b, -eeb);
      Ea = za ? ELa : (Ea - eea);
      Eb = zb ? ELb : (Eb - eeb);
    }
  };

  // ---- prologue: per chain, sets 0..2 <- blocks 0..2; stage+gather block 0;
  //      set0 <- block 3 ----
  float4 SA0[4], SA1[4], SA2[4], SB0[4], SB1[4], SB2[4];
  gload(rpA, SA0, 0); gload(rpA, SA1, 1); gload(rpA, SA2, 2);
  gload(rpB, SB0, 0); gload(rpB, SB1, 1); gload(rpB, SB2, 2);
  prep(SA0, ringA, 0, blA[0], SaccA);
  gath(ringA, 0, xpa, xsa, r1A[0], r2A[0]);
  gload(rpA, SA0, 3);
  prep(SB0, ringB, 0, blB[0], SaccB);
  gath(ringB, 0, xpb, xsb, r1B[0], r2B[0]);
  gload(rpB, SB0, 3);
  // virtual init: one DP step from (A0=1@lane0) yields exact alpha(t=0)
  A0a = (lane == 0) ? 1.f : 0.f; A1a = 0.f; A2a = 0.f;
  A0b = A0a; A1b = 0.f; A2b = 0.f;

  // body(n): stage block n+1 (bank (n+1)&1) for both chains, issue gathers
  // (consumed next body), reload freed sets with block n+4, then run the
  // interleaved 8 steps of block n.
  auto body = [&](int n, float4 (&SsA)[4], float4 (&SsB)[4],
                  int cur, int nxt, bool doStage) {
    if (doStage) {
      const int bk = (n + 1) & 1;
      prep(SsA, ringA, bk, blA[nxt], SaccA);
      gath(ringA, bk, xpa, xsa, r1A[nxt], r2A[nxt]);
      gload(rpA, SsA, n + 4);
      prep(SsB, ringB, bk, blB[nxt], SaccB);
      gath(ringB, bk, xpb, xsb, r1B[nxt], r2B[nxt]);
      gload(rpB, SsB, n + 4);
    }
    dp8_2(r1A[cur], r2A[cur], blA[cur], r1B[cur], r2B[cur], blB[cur]);
  };

  for (int nn = 0; nn < 60; nn += 6) {
    body(nn + 0, SA1, SB1, 0, 1, true);
    body(nn + 1, SA2, SB2, 1, 0, true);
    body(nn + 2, SA0, SB0, 0, 1, true);
    body(nn + 3, SA1, SB1, 1, 0, true);
    body(nn + 4, SA2, SB2, 0, 1, true);
    body(nn + 5, SA0, SB0, 1, 0, true);
  }
  body(60, SA1, SB1, 0, 1, true);
  body(61, SA2, SB2, 1, 0, true);
  body(62, SA0, SB0, 0, 1, true);
  body(63, SA1, SB1, 1, 0, false);      // last block: no staging/prefetch

  // ---- denominator totals (each row counted 8x -> *0.125) ----
  auto reduceS = [&](float s) {
    s += dpp_f<DPP_XOR1>(s);
    s += dpp_f<DPP_XOR2>(s);
    s += dpp_f<DPP_HMIRR>(s);
    s += dpp_f<DPP_MIRR>(s);
    s += __shfl_xor(s, 16, 64);
    s += __shfl_xor(s, 32, 64);
    return s * 0.125f;
  };
  const float StotA = reduceS(SaccA);
  const float StotB = reduceS(SaccB);

  // loss = ln2 * (S - (log2(A159+A160) - E));  lane 53: A0=s159, A1=s160
  if (lane == 53) {
    out[ba] = LN2_ * (StotA - (LOG2F(A0a + A1a) - (float)Ea));
    out[bb] = LN2_ * (StotB - (LOG2F(A0b + A1b) - (float)Eb));
  }
}

extern "C" void kernel_launch(void* const* d_in, const int* in_sizes, int n_in,
                              void* d_out, int out_size, void* d_ws, size_t ws_size,
                              hipStream_t stream) {
  const int*   labels = (const int*)d_in[0];    // y_true [B,L]
  const float* y_pred = (const float*)d_in[1];  // y_pred [B,T,C]
  float*       out    = (float*)d_out;          // [B,1]
  ctc_fused<<<dim3(B_ / 2), dim3(64), 0, stream>>>(labels, y_pred, out);
}